// Round 7
// baseline (312.807 us; speedup 1.0000x reference)
//
#include <hip/hip_runtime.h>
#include <math.h>

namespace {
constexpr int kB = 16, kH = 64, kW = 64, kC = 512;
constexpr int kR = 256, kN = 64, kPH = 7, kPW = 7;
constexpr int kC4 = kC / 4;              // 128 float4 channel groups
constexpr float kIouThr = 0.4f;
constexpr size_t kPooledElems = (size_t)kB * kN * kPH * kPW * kC; // 25,690,112
}

__device__ __forceinline__ float4 max4(float4 a, float4 b) {
    return make_float4(fmaxf(a.x, b.x), fmaxf(a.y, b.y),
                       fmaxf(a.z, b.z), fmaxf(a.w, b.w));
}

// One block (256 threads) per batch. Bitmask NMS + clip + LPT sort:
//   phase 1: thread i computes 256-bit row mask M[i] (iou(i,j) > thr), parallel.
//   phase 2: thread 0 does the greedy scan with pure register ops + LDS prefetch.
//   phase 3: parallel rank/select, then clip, write roi_clipped to d_out tail.
//   phase 4: bitonic sort of the 64 kept regions by clipped area DESCENDING,
//            permutation -> perm[b*64+rank]. Pool dispatches big regions first
//            (LPT): R6 measured 32% occupancy = decaying tail from ~8x item
//            cost variance; ordering is the only fix (HW backfill is greedy
//            but can't avoid starting a worst item in the last round).
__global__ __launch_bounds__(256) void nms_clip_kernel(
        const float* __restrict__ roi, float* __restrict__ out_roi,
        int* __restrict__ perm) {
    const int b = blockIdx.x;
    const int tid = threadIdx.x;                  // 0..255 = box index
    const float* r = roi + (size_t)b * kR * 4;

    __shared__ float4 box[kR];                    // x1,y1,x2,y2
    __shared__ float area[kR];
    __shared__ unsigned long long M[kR][4];
    __shared__ unsigned long long kw[4];
    __shared__ int idx[kN];
    __shared__ int skey[kN];                      // (clip_area<<6)|slot

    if (tid < kN) idx[tid] = kR - kN + tid;       // fill = 192+k

    const float4 rr = ((const float4*)r)[tid];    // x,y,w,h
    const float x1 = rr.x, y1 = rr.y, x2 = rr.x + rr.z, y2 = rr.y + rr.w;
    box[tid] = make_float4(x1, y1, x2, y2);
    area[tid] = (y2 - y1) * (x2 - x1);
    __syncthreads();

    // phase 1: row masks
    {
        unsigned long long m0 = 0, m1 = 0, m2 = 0, m3 = 0;
        const float ai = area[tid];
        for (int j = 0; j < kR; ++j) {
            const float4 bj = box[j];             // LDS broadcast (uniform j)
            const float ih = fmaxf(fminf(y2, bj.w) - fmaxf(y1, bj.y), 0.0f);
            const float iw = fmaxf(fminf(x2, bj.z) - fmaxf(x1, bj.x), 0.0f);
            const float inter = ih * iw;
            const float uni = ai + area[j] - inter;
            const float iou = (uni > 0.0f) ? (inter / uni) : 0.0f;
            if (iou > kIouThr) {
                const unsigned long long bit = 1ull << (j & 63);
                if ((j >> 6) == 0) m0 |= bit;
                else if ((j >> 6) == 1) m1 |= bit;
                else if ((j >> 6) == 2) m2 |= bit;
                else m3 |= bit;
            }
        }
        M[tid][0] = m0; M[tid][1] = m1; M[tid][2] = m2; M[tid][3] = m3;
    }
    __syncthreads();

    // phase 2: greedy scan (sequential, single thread, register-only chain)
    if (tid == 0) {
        unsigned long long s0 = 0, s1 = 0, s2 = 0, s3 = 0;
        unsigned long long k0 = 0, k1 = 0, k2 = 0, k3 = 0;
        unsigned long long n0 = M[0][0], n1 = M[0][1], n2 = M[0][2], n3 = M[0][3];
#pragma unroll
        for (int wi = 0; wi < 4; ++wi) {
            for (int bi = 0; bi < 64; ++bi) {
                const unsigned long long m0 = n0, m1 = n1, m2 = n2, m3 = n3;
                const int ip = (wi * 64 + bi + 1) & 255;   // prefetch next row
                n0 = M[ip][0]; n1 = M[ip][1]; n2 = M[ip][2]; n3 = M[ip][3];
                const unsigned long long sw =
                    (wi == 0) ? s0 : (wi == 1) ? s1 : (wi == 2) ? s2 : s3;
                if (!((sw >> bi) & 1ull)) {
                    const unsigned long long bit = 1ull << bi;
                    if (wi == 0) k0 |= bit;
                    else if (wi == 1) k1 |= bit;
                    else if (wi == 2) k2 |= bit;
                    else k3 |= bit;
                    s0 |= m0; s1 |= m1; s2 |= m2; s3 |= m3;
                }
            }
        }
        kw[0] = k0; kw[1] = k1; kw[2] = k2; kw[3] = k3;
    }
    __syncthreads();

    // phase 3: rank + scatter
    {
        const int wi = tid >> 6, bi = tid & 63;
        const unsigned long long kwv = kw[wi];
        if ((kwv >> bi) & 1ull) {
            int rank = 0;
            for (int w2 = 0; w2 < wi; ++w2) rank += __popcll(kw[w2]);
            const unsigned long long below =
                (bi == 0) ? 0ull : (~0ull >> (64 - bi));
            rank += __popcll(kwv & below);
            if (rank < kN) idx[rank] = tid;
        }
    }
    __syncthreads();

    if (tid < kN) {
        const int i = idx[tid];
        const float x = r[i * 4 + 0], y = r[i * 4 + 1];
        const float w = r[i * 4 + 2], h = r[i * 4 + 3];
        int x_min = (int)fmaxf(0.0f, x);
        int y_min = (int)fmaxf(0.0f, y);
        int x_max = (int)fminf((float)kW, x + w);
        int y_max = (int)fminf((float)kH, y + h);
        // _fix_axis(ps=7, fs=64); >>1 matches Python floor-div by 2
        {
            const int pad = kPW - (x_max - x_min);
            const bool fmn = x_min < (pad >> 1);
            const bool fmx = (kW - x_max) < ((1 + pad) >> 1);
            const bool sym = (pad > 0) && !(fmn || fmx);
            int omin = sym ? (x_min - (pad >> 1)) : x_min;
            int omax = sym ? (x_max + ((1 + pad) >> 1)) : x_max;
            if ((pad > 0) && fmn) { omin = 0; omax = kPW; }
            if ((pad > 0) && fmx) { omin = kW - kPW; omax = kW; }
            x_min = omin; x_max = omax;
        }
        {
            const int pad = kPH - (y_max - y_min);
            const bool fmn = y_min < (pad >> 1);
            const bool fmx = (kH - y_max) < ((1 + pad) >> 1);
            const bool sym = (pad > 0) && !(fmn || fmx);
            int omin = sym ? (y_min - (pad >> 1)) : y_min;
            int omax = sym ? (y_max + ((1 + pad) >> 1)) : y_max;
            if ((pad > 0) && fmn) { omin = 0; omax = kPH; }
            if ((pad > 0) && fmx) { omin = kH - kPH; omax = kH; }
            y_min = omin; y_max = omax;
        }
        float4 rf;
        rf.x = (float)x_min; rf.y = (float)y_min;
        rf.z = (float)(x_max - x_min); rf.w = (float)(y_max - y_min);
        ((float4*)out_roi)[b * kN + tid] = rf;

        // phase 4 key: clipped area (cost proxy), tie-broken by slot ->
        // guaranteed full permutation regardless of equal areas.
        skey[tid] = (((x_max - x_min) * (y_max - y_min)) << 6) | tid;
    }
    __syncthreads();

    // bitonic sort, 64 keys, DESCENDING (barriers uniform across all 256 thr)
    for (int k = 2; k <= kN; k <<= 1) {
        for (int j = k >> 1; j > 0; j >>= 1) {
            if (tid < kN) {
                const int ixj = tid ^ j;
                if (ixj > tid) {
                    const int a = skey[tid], c = skey[ixj];
                    const bool up = (tid & k) == 0;   // up-blocks: larger first
                    if (up ? (a < c) : (a > c)) { skey[tid] = c; skey[ixj] = a; }
                }
            }
            __syncthreads();
        }
    }
    if (tid < kN) perm[b * kN + tid] = skey[tid] & 63;
}

// Four blocks per (b, region) — one per 32-group channel quarter. 256 threads
// = 8 row-sections x 32 channel groups.
// LPT dispatch: rank r within a batch maps to the r-th LARGEST clipped region
// (perm from nms). blockIdx order round-robins the 8 XCD chunks and walks
// ranks ascending, so the costliest items start first and small items fill
// the tail (R6: 32% occupancy = tail of big items started late).
// Traffic is compulsory (R6: FETCH 139 MB vs 128 MB map, WRITE exact); the
// only remaining lever is schedule shape.
// NO min-waves launch_bounds: clamping VGPR<~44 spills pm[7] -> +150 MB HBM.
// XCD chunk swizzle kept: R2-vs-R4 A/B showed -32 MB FETCH.
__global__ __launch_bounds__(256) void pool_kernel(
        const float4* __restrict__ fm4, const float4* __restrict__ rcf,
        const int* __restrict__ perm, float4* __restrict__ out4) {
    const int chunk = blockIdx.x & 7;             // XCD chunk (2 batches)
    const int u = blockIdx.x >> 3;                // 0..511 within chunk
    const int slot = u >> 2;                      // 0..127
    const int q4 = u & 3;                         // channel quarter 0..3
    const int batch = chunk * 2 + (slot & 1);     // interleave chunk's batches
    const int rank = slot >> 1;                   // 0 = largest region
    const int rid = batch * kN + perm[batch * kN + rank];
    const int b = batch;
    const int tid = threadIdx.x;
    const int s = tid >> 5;                       // row section 0..7
    const int t = tid & 31;                       // group within quarter
    const int g = q4 * 32 + t;                    // channel group 0..127

    const float4 rf = rcf[rid];
    const int x = (int)rf.x, y = (int)rf.y;
    const int w = (int)rf.z, h = (int)rf.w;       // w,h >= 7 guaranteed

    const float4* fm = fm4 + (size_t)b * kH * kW * kC4 + g;
    float4* out = out4 + (size_t)rid * (kPH * kPW) * kC4 + g;

    const float NI = -__builtin_inff();
    const float4 ninf = make_float4(NI, NI, NI, NI);

    // top rows p=0..5: one row per section (sections 6,7 go straight to bottom)
    if (s < 6) {
        const int p = s;
        const float4* row = fm + ((y + p) * kW + x) * kC4;
        float4 v0 = row[0 * kC4], v1 = row[1 * kC4], v2 = row[2 * kC4];
        float4 v3 = row[3 * kC4], v4 = row[4 * kC4], v5 = row[5 * kC4];
        out[(p * 7 + 0) * kC4] = v0;
        out[(p * 7 + 1) * kC4] = v1;
        out[(p * 7 + 2) * kC4] = v2;
        out[(p * 7 + 3) * kC4] = v3;
        out[(p * 7 + 4) * kC4] = v4;
        out[(p * 7 + 5) * kC4] = v5;
        float4 m0 = ninf, m1 = ninf, m2 = ninf, m3 = ninf;
        int j = 6;
        for (; j + 4 <= w; j += 4) {              // 4 independent chains
            float4 a0 = row[(j + 0) * kC4], a1 = row[(j + 1) * kC4];
            float4 a2 = row[(j + 2) * kC4], a3 = row[(j + 3) * kC4];
            m0 = max4(m0, a0); m1 = max4(m1, a1);
            m2 = max4(m2, a2); m3 = max4(m3, a3);
        }
        for (; j < w; ++j) m0 = max4(m0, row[j * kC4]);
        out[(p * 7 + 6) * kC4] = max4(max4(m0, m1), max4(m2, m3));
    }

    // bottom rows i in [y+6, y+h): strided by section (8-way)
    float4 pm[7];
#pragma unroll
    for (int o = 0; o < 7; ++o) pm[o] = ninf;
    for (int i = y + 6 + s; i < y + h; i += 8) {
        const float4* row = fm + (i * kW + x) * kC4;
#pragma unroll
        for (int q = 0; q < 6; ++q) pm[q] = max4(pm[q], row[q * kC4]);
        float4 c0 = pm[6], c1 = ninf, c2 = ninf, c3 = ninf;
        int j = 6;
        for (; j + 4 <= w; j += 4) {              // 4 independent chains
            float4 a0 = row[(j + 0) * kC4], a1 = row[(j + 1) * kC4];
            float4 a2 = row[(j + 2) * kC4], a3 = row[(j + 3) * kC4];
            c0 = max4(c0, a0); c1 = max4(c1, a1);
            c2 = max4(c2, a2); c3 = max4(c3, a3);
        }
        for (; j < w; ++j) c0 = max4(c0, row[j * kC4]);
        pm[6] = max4(max4(c0, c1), max4(c2, c3));
    }

    // 8 -> 4 -> 2 -> 1 tree reduction, one reused [4][7][32] buffer (14336 B)
    __shared__ float4 red[4][kPH][32];
    if (s >= 4) {
#pragma unroll
        for (int o = 0; o < 7; ++o) red[s - 4][o][t] = pm[o];
    }
    __syncthreads();
    if (s < 4) {
#pragma unroll
        for (int o = 0; o < 7; ++o) pm[o] = max4(pm[o], red[s][o][t]);
    }
    __syncthreads();
    if (s == 2 || s == 3) {
#pragma unroll
        for (int o = 0; o < 7; ++o) red[s - 2][o][t] = pm[o];
    }
    __syncthreads();
    if (s < 2) {
#pragma unroll
        for (int o = 0; o < 7; ++o) pm[o] = max4(pm[o], red[s][o][t]);
    }
    __syncthreads();
    if (s == 1) {
#pragma unroll
        for (int o = 0; o < 7; ++o) red[0][o][t] = pm[o];
    }
    __syncthreads();
    if (s == 0) {
#pragma unroll
        for (int o = 0; o < 7; ++o) {
            out[(42 + o) * kC4] = max4(pm[o], red[0][o][t]);
        }
    }
}

extern "C" void kernel_launch(void* const* d_in, const int* in_sizes, int n_in,
                              void* d_out, int out_size, void* d_ws, size_t ws_size,
                              hipStream_t stream) {
    (void)in_sizes; (void)n_in; (void)ws_size; (void)out_size;
    const float* features = (const float*)d_in[0];
    const float* roi = (const float*)d_in[1];
    float* out = (float*)d_out;
    float* out_roi = out + kPooledElems;          // roi_clipped tail
    int* perm = (int*)d_ws;                       // 1024 ints, written by nms

    nms_clip_kernel<<<kB, 256, 0, stream>>>(roi, out_roi, perm);
    pool_kernel<<<kB * kN * 4, 256, 0, stream>>>(
        (const float4*)features, (const float4*)out_roi, perm, (float4*)out);
}

// Round 10
// 307.144 us; speedup vs baseline: 1.0184x; 1.0184x over previous
//
#include <hip/hip_runtime.h>
#include <math.h>

namespace {
constexpr int kB = 16, kH = 64, kW = 64, kC = 512;
constexpr int kR = 256, kN = 64, kPH = 7, kPW = 7;
constexpr int kC4 = kC / 4;              // 128 float4 channel groups
constexpr float kIouThr = 0.4f;
constexpr size_t kPooledElems = (size_t)kB * kN * kPH * kPW * kC; // 25,690,112
}

__device__ __forceinline__ float4 max4(float4 a, float4 b) {
    return make_float4(fmaxf(a.x, b.x), fmaxf(a.y, b.y),
                       fmaxf(a.z, b.z), fmaxf(a.w, b.w));
}

// One block (256 threads) per batch. Bitmask NMS + clip + LPT sort:
//   phase 1: thread i computes 256-bit row mask M[i] (iou(i,j) > thr), parallel.
//   phase 2: thread 0 does the greedy scan with pure register ops + LDS prefetch.
//   phase 3: parallel rank/select, then clip, write roi_clipped to d_out tail.
//   phase 4: bitonic sort of the 64 kept regions by clipped area DESCENDING,
//            permutation -> perm[b*64+rank]. Pool dispatches big regions first.
__global__ __launch_bounds__(256) void nms_clip_kernel(
        const float* __restrict__ roi, float* __restrict__ out_roi,
        int* __restrict__ perm) {
    const int b = blockIdx.x;
    const int tid = threadIdx.x;                  // 0..255 = box index
    const float* r = roi + (size_t)b * kR * 4;

    __shared__ float4 box[kR];                    // x1,y1,x2,y2
    __shared__ float area[kR];
    __shared__ unsigned long long M[kR][4];
    __shared__ unsigned long long kw[4];
    __shared__ int idx[kN];
    __shared__ int skey[kN];                      // (clip_area<<6)|slot

    if (tid < kN) idx[tid] = kR - kN + tid;       // fill = 192+k

    const float4 rr = ((const float4*)r)[tid];    // x,y,w,h
    const float x1 = rr.x, y1 = rr.y, x2 = rr.x + rr.z, y2 = rr.y + rr.w;
    box[tid] = make_float4(x1, y1, x2, y2);
    area[tid] = (y2 - y1) * (x2 - x1);
    __syncthreads();

    // phase 1: row masks
    {
        unsigned long long m0 = 0, m1 = 0, m2 = 0, m3 = 0;
        const float ai = area[tid];
        for (int j = 0; j < kR; ++j) {
            const float4 bj = box[j];             // LDS broadcast (uniform j)
            const float ih = fmaxf(fminf(y2, bj.w) - fmaxf(y1, bj.y), 0.0f);
            const float iw = fmaxf(fminf(x2, bj.z) - fmaxf(x1, bj.x), 0.0f);
            const float inter = ih * iw;
            const float uni = ai + area[j] - inter;
            const float iou = (uni > 0.0f) ? (inter / uni) : 0.0f;
            if (iou > kIouThr) {
                const unsigned long long bit = 1ull << (j & 63);
                if ((j >> 6) == 0) m0 |= bit;
                else if ((j >> 6) == 1) m1 |= bit;
                else if ((j >> 6) == 2) m2 |= bit;
                else m3 |= bit;
            }
        }
        M[tid][0] = m0; M[tid][1] = m1; M[tid][2] = m2; M[tid][3] = m3;
    }
    __syncthreads();

    // phase 2: greedy scan (sequential, single thread, register-only chain)
    if (tid == 0) {
        unsigned long long s0 = 0, s1 = 0, s2 = 0, s3 = 0;
        unsigned long long k0 = 0, k1 = 0, k2 = 0, k3 = 0;
        unsigned long long n0 = M[0][0], n1 = M[0][1], n2 = M[0][2], n3 = M[0][3];
#pragma unroll
        for (int wi = 0; wi < 4; ++wi) {
            for (int bi = 0; bi < 64; ++bi) {
                const unsigned long long m0 = n0, m1 = n1, m2 = n2, m3 = n3;
                const int ip = (wi * 64 + bi + 1) & 255;   // prefetch next row
                n0 = M[ip][0]; n1 = M[ip][1]; n2 = M[ip][2]; n3 = M[ip][3];
                const unsigned long long sw =
                    (wi == 0) ? s0 : (wi == 1) ? s1 : (wi == 2) ? s2 : s3;
                if (!((sw >> bi) & 1ull)) {
                    const unsigned long long bit = 1ull << bi;
                    if (wi == 0) k0 |= bit;
                    else if (wi == 1) k1 |= bit;
                    else if (wi == 2) k2 |= bit;
                    else k3 |= bit;
                    s0 |= m0; s1 |= m1; s2 |= m2; s3 |= m3;
                }
            }
        }
        kw[0] = k0; kw[1] = k1; kw[2] = k2; kw[3] = k3;
    }
    __syncthreads();

    // phase 3: rank + scatter
    {
        const int wi = tid >> 6, bi = tid & 63;
        const unsigned long long kwv = kw[wi];
        if ((kwv >> bi) & 1ull) {
            int rank = 0;
            for (int w2 = 0; w2 < wi; ++w2) rank += __popcll(kw[w2]);
            const unsigned long long below =
                (bi == 0) ? 0ull : (~0ull >> (64 - bi));
            rank += __popcll(kwv & below);
            if (rank < kN) idx[rank] = tid;
        }
    }
    __syncthreads();

    if (tid < kN) {
        const int i = idx[tid];
        const float x = r[i * 4 + 0], y = r[i * 4 + 1];
        const float w = r[i * 4 + 2], h = r[i * 4 + 3];
        int x_min = (int)fmaxf(0.0f, x);
        int y_min = (int)fmaxf(0.0f, y);
        int x_max = (int)fminf((float)kW, x + w);
        int y_max = (int)fminf((float)kH, y + h);
        // _fix_axis(ps=7, fs=64); >>1 matches Python floor-div by 2
        {
            const int pad = kPW - (x_max - x_min);
            const bool fmn = x_min < (pad >> 1);
            const bool fmx = (kW - x_max) < ((1 + pad) >> 1);
            const bool sym = (pad > 0) && !(fmn || fmx);
            int omin = sym ? (x_min - (pad >> 1)) : x_min;
            int omax = sym ? (x_max + ((1 + pad) >> 1)) : x_max;
            if ((pad > 0) && fmn) { omin = 0; omax = kPW; }
            if ((pad > 0) && fmx) { omin = kW - kPW; omax = kW; }
            x_min = omin; x_max = omax;
        }
        {
            const int pad = kPH - (y_max - y_min);
            const bool fmn = y_min < (pad >> 1);
            const bool fmx = (kH - y_max) < ((1 + pad) >> 1);
            const bool sym = (pad > 0) && !(fmn || fmx);
            int omin = sym ? (y_min - (pad >> 1)) : y_min;
            int omax = sym ? (y_max + ((1 + pad) >> 1)) : y_max;
            if ((pad > 0) && fmn) { omin = 0; omax = kPH; }
            if ((pad > 0) && fmx) { omin = kH - kPH; omax = kH; }
            y_min = omin; y_max = omax;
        }
        float4 rf;
        rf.x = (float)x_min; rf.y = (float)y_min;
        rf.z = (float)(x_max - x_min); rf.w = (float)(y_max - y_min);
        ((float4*)out_roi)[b * kN + tid] = rf;

        // phase 4 key: clipped area (cost proxy), tie-broken by slot ->
        // guaranteed full permutation regardless of equal areas.
        skey[tid] = (((x_max - x_min) * (y_max - y_min)) << 6) | tid;
    }
    __syncthreads();

    // bitonic sort, 64 keys, DESCENDING (barriers uniform across all 256 thr)
    for (int k = 2; k <= kN; k <<= 1) {
        for (int j = k >> 1; j > 0; j >>= 1) {
            if (tid < kN) {
                const int ixj = tid ^ j;
                if (ixj > tid) {
                    const int a = skey[tid], c = skey[ixj];
                    const bool up = (tid & k) == 0;   // up-blocks: larger first
                    if (up ? (a < c) : (a > c)) { skey[tid] = c; skey[ixj] = a; }
                }
            }
            __syncthreads();
        }
    }
    if (tid < kN) perm[b * kN + tid] = skey[tid] & 63;
}

// Four blocks per (b, region) — one per 32-group channel quarter. 256 threads
// = 8 row-sections x 32 channel groups.
// Dispatch = XCD chunk (outer) -> batch SEQUENTIAL (2 per chunk) -> LPT rank
// ascending -> quarter. R7's batch-INTERLEAVED LPT put 2 maps (16 MB) in the
// 4 MiB XCD-L2 concurrently: FETCH 139->173 MB, eating the schedule gain.
// Batch-sequential keeps one ~8 MB map hot per phase (R6 locality, FETCH
// ~1.08x compulsory) while LPT-within-batch still front-loads big regions;
// batch A's tail overlaps batch B's head via in-order backfill.
// Traffic is compulsory (reads = map-once, WRITE exact); schedule shape is
// the only lever. BW/occupancy ratio stable ~0.085 TB/s per point across
// R5/R6/R7 -> still occupancy-limited, not pattern-capped.
// NO min-waves launch_bounds: clamping VGPR<~44 spills pm[7] -> +150 MB HBM.
// VGPR must stay <=64 (56 now) or waves/CU halve.
__global__ __launch_bounds__(256) void pool_kernel(
        const float4* __restrict__ fm4, const float4* __restrict__ rcf,
        const int* __restrict__ perm, float4* __restrict__ out4) {
    const int chunk = blockIdx.x & 7;             // XCD chunk (2 batches)
    const int u = blockIdx.x >> 3;                // 0..511 within chunk
    const int slot = u >> 2;                      // 0..127
    const int q4 = u & 3;                         // channel quarter 0..3
    const int batch = chunk * 2 + (slot >> 6);    // batch-SEQUENTIAL in chunk
    const int rank = slot & 63;                   // 0 = largest region
    const int rid = batch * kN + perm[batch * kN + rank];
    const int b = batch;
    const int tid = threadIdx.x;
    const int s = tid >> 5;                       // row section 0..7
    const int t = tid & 31;                       // group within quarter
    const int g = q4 * 32 + t;                    // channel group 0..127

    const float4 rf = rcf[rid];
    const int x = (int)rf.x, y = (int)rf.y;
    const int w = (int)rf.z, h = (int)rf.w;       // w,h >= 7 guaranteed

    const float4* fm = fm4 + (size_t)b * kH * kW * kC4 + g;
    float4* out = out4 + (size_t)rid * (kPH * kPW) * kC4 + g;

    const float NI = -__builtin_inff();
    const float4 ninf = make_float4(NI, NI, NI, NI);

    // top rows p=0..5: one row per section (sections 6,7 go straight to bottom)
    if (s < 6) {
        const int p = s;
        const float4* row = fm + ((y + p) * kW + x) * kC4;
        float4 v0 = row[0 * kC4], v1 = row[1 * kC4], v2 = row[2 * kC4];
        float4 v3 = row[3 * kC4], v4 = row[4 * kC4], v5 = row[5 * kC4];
        out[(p * 7 + 0) * kC4] = v0;
        out[(p * 7 + 1) * kC4] = v1;
        out[(p * 7 + 2) * kC4] = v2;
        out[(p * 7 + 3) * kC4] = v3;
        out[(p * 7 + 4) * kC4] = v4;
        out[(p * 7 + 5) * kC4] = v5;
        float4 m0 = ninf, m1 = ninf, m2 = ninf, m3 = ninf;
        int j = 6;
        for (; j + 4 <= w; j += 4) {              // 4 independent chains
            float4 a0 = row[(j + 0) * kC4], a1 = row[(j + 1) * kC4];
            float4 a2 = row[(j + 2) * kC4], a3 = row[(j + 3) * kC4];
            m0 = max4(m0, a0); m1 = max4(m1, a1);
            m2 = max4(m2, a2); m3 = max4(m3, a3);
        }
        for (; j < w; ++j) m0 = max4(m0, row[j * kC4]);
        out[(p * 7 + 6) * kC4] = max4(max4(m0, m1), max4(m2, m3));
    }

    // bottom rows i in [y+6, y+h): strided by section (8-way)
    float4 pm[7];
#pragma unroll
    for (int o = 0; o < 7; ++o) pm[o] = ninf;
    for (int i = y + 6 + s; i < y + h; i += 8) {
        const float4* row = fm + (i * kW + x) * kC4;
#pragma unroll
        for (int q = 0; q < 6; ++q) pm[q] = max4(pm[q], row[q * kC4]);
        float4 c0 = pm[6], c1 = ninf, c2 = ninf, c3 = ninf;
        int j = 6;
        for (; j + 4 <= w; j += 4) {              // 4 independent chains
            float4 a0 = row[(j + 0) * kC4], a1 = row[(j + 1) * kC4];
            float4 a2 = row[(j + 2) * kC4], a3 = row[(j + 3) * kC4];
            c0 = max4(c0, a0); c1 = max4(c1, a1);
            c2 = max4(c2, a2); c3 = max4(c3, a3);
        }
        for (; j < w; ++j) c0 = max4(c0, row[j * kC4]);
        pm[6] = max4(max4(c0, c1), max4(c2, c3));
    }

    // 8 -> 4 -> 2 -> 1 tree reduction, one reused [4][7][32] buffer (14336 B)
    __shared__ float4 red[4][kPH][32];
    if (s >= 4) {
#pragma unroll
        for (int o = 0; o < 7; ++o) red[s - 4][o][t] = pm[o];
    }
    __syncthreads();
    if (s < 4) {
#pragma unroll
        for (int o = 0; o < 7; ++o) pm[o] = max4(pm[o], red[s][o][t]);
    }
    __syncthreads();
    if (s == 2 || s == 3) {
#pragma unroll
        for (int o = 0; o < 7; ++o) red[s - 2][o][t] = pm[o];
    }
    __syncthreads();
    if (s < 2) {
#pragma unroll
        for (int o = 0; o < 7; ++o) pm[o] = max4(pm[o], red[s][o][t]);
    }
    __syncthreads();
    if (s == 1) {
#pragma unroll
        for (int o = 0; o < 7; ++o) red[0][o][t] = pm[o];
    }
    __syncthreads();
    if (s == 0) {
#pragma unroll
        for (int o = 0; o < 7; ++o) {
            out[(42 + o) * kC4] = max4(pm[o], red[0][o][t]);
        }
    }
}

extern "C" void kernel_launch(void* const* d_in, const int* in_sizes, int n_in,
                              void* d_out, int out_size, void* d_ws, size_t ws_size,
                              hipStream_t stream) {
    (void)in_sizes; (void)n_in; (void)ws_size; (void)out_size;
    const float* features = (const float*)d_in[0];
    const float* roi = (const float*)d_in[1];
    float* out = (float*)d_out;
    float* out_roi = out + kPooledElems;          // roi_clipped tail
    int* perm = (int*)d_ws;                       // 1024 ints, written by nms

    nms_clip_kernel<<<kB, 256, 0, stream>>>(roi, out_roi, perm);
    pool_kernel<<<kB * kN * 4, 256, 0, stream>>>(
        (const float4*)features, (const float4*)out_roi, perm, (float4*)out);
}